// Round 15
// baseline (230.753 us; speedup 1.0000x reference)
//
#include <hip/hip_runtime.h>
#include <hip/hip_fp16.h>
#include <hip/hip_cooperative_groups.h>

#define NN 100000
#define NE 1600000
#define FI 32
#define FH 30
#define PAD 32       // row stride (elements) for fp32 feature arrays
#define NG 512
#define NBK 782      // ceil(NN/128) buckets of 128 consecutive dst nodes
#define BNODES 128
#define SCB 1024     // blocks for hist/scatter grid-stride
#define CBLK 32      // blocks per prefix chunk
#define NCHUNK (SCB / CBLK)   // 32
#define CAP 4096     // per-bucket LDS staging capacity (mean 2046)
#define NB1 391      // ceil(NN/256)
#define F8B 3125     // fp8-convert blocks: NN*8 words / 256
#define PFB 98       // prefix kernel blocks: ceil(NCHUNK*NBK/256)

// ---------- per-block bucket histogram (blocks < SCB) + x fp32->fp8 convert (rest) ----------
__global__ __launch_bounds__(256) void k_phist(const int* __restrict__ dst,
                                               unsigned short* __restrict__ partial,
                                               const float* __restrict__ x, unsigned* __restrict__ x8)
{
    __shared__ int cnt[NBK];
    if (blockIdx.x >= SCB) {
        int i = (blockIdx.x - SCB) * 256 + threadIdx.x;   // uint word = 4 fp8
        if (i < NN * 8) {
            float4 f = ((const float4*)x)[i];
            unsigned w = 0;
            w = __builtin_amdgcn_cvt_pk_fp8_f32(f.x, f.y, w, false);
            w = __builtin_amdgcn_cvt_pk_fp8_f32(f.z, f.w, w, true);
            x8[i] = w;
        }
        return;
    }
    for (int i = threadIdx.x; i < NBK; i += 256) cnt[i] = 0;
    __syncthreads();
    for (int e = blockIdx.x * 256 + threadIdx.x; e < NE; e += SCB * 256)
        atomicAdd(&cnt[dst[e] >> 7], 1);
    __syncthreads();
    for (int i = threadIdx.x; i < NBK; i += 256)
        partial[(size_t)blockIdx.x * NBK + i] = (unsigned short)cnt[i];
}

// ---------- fused prefix (cooperative): chunk sums -> bucket scan -> per-block bases ----------
__global__ __launch_bounds__(256) void k_prefix(unsigned short* __restrict__ partial,
                                                int* __restrict__ chunksum,
                                                int* __restrict__ bktOff)
{
    cooperative_groups::grid_group grid = cooperative_groups::this_grid();
    int t = blockIdx.x * 256 + threadIdx.x;
    int c = t / NBK, b = t - (t / NBK) * NBK;
    // phase 1: chunksum[c][b] = sum of partial over the chunk's CBLK blocks
    if (t < NCHUNK * NBK) {
        int s = 0;
        #pragma unroll 8
        for (int k = 0; k < CBLK; ++k)
            s += partial[(size_t)(c * CBLK + k) * NBK + b];
        chunksum[c * NBK + b] = s;
    }
    grid.sync();
    // phase 2 (block 0): bucket totals + inclusive scan -> bktOff[1..NBK], bktOff[0]=0
    if (blockIdx.x == 0) {
        __shared__ int tot[NBK];
        int tid = threadIdx.x;
        for (int i = tid; i < NBK; i += 256) {
            int s = 0;
            for (int cc = 0; cc < NCHUNK; ++cc) s += chunksum[cc * NBK + i];
            tot[i] = s;
        }
        __syncthreads();
        for (int off = 1; off < NBK; off <<= 1) {
            int vals[(NBK + 255) / 256];
            for (int i = tid, j = 0; i < NBK; i += 256, ++j)
                vals[j] = (i >= off) ? tot[i - off] : 0;
            __syncthreads();
            for (int i = tid, j = 0; i < NBK; i += 256, ++j)
                tot[i] += vals[j];
            __syncthreads();
        }
        for (int i = tid; i < NBK; i += 256) bktOff[i + 1] = tot[i];
        if (tid == 0) bktOff[0] = 0;
    }
    // phase 3: partial[blk][b] <- within-bucket write base (needs only chunksum)
    if (t < NCHUNK * NBK) {
        int run = 0;
        for (int cc = 0; cc < c; ++cc) run += chunksum[cc * NBK + b];
        #pragma unroll 8
        for (int k = 0; k < CBLK; ++k) {
            size_t idx = (size_t)(c * CBLK + k) * NBK + b;
            int vv = partial[idx];
            partial[idx] = (unsigned short)run;
            run += vv;
        }
    }
}

// ---------- single-pass bucketed scatter using precomputed bases ----------
__global__ __launch_bounds__(256) void k_bscat(const int* __restrict__ src, const int* __restrict__ dst,
                                               const unsigned short* __restrict__ partial,
                                               const int* __restrict__ bktOff,
                                               unsigned* __restrict__ pairs)
{
    __shared__ int sbase[NBK];
    __shared__ int scnt[NBK];
    for (int i = threadIdx.x; i < NBK; i += 256) {
        sbase[i] = bktOff[i] + (int)partial[(size_t)blockIdx.x * NBK + i];
        scnt[i] = 0;
    }
    __syncthreads();
    for (int e = blockIdx.x * 256 + threadIdx.x; e < NE; e += SCB * 256) {
        int d = dst[e];
        int b = d >> 7;
        int r = atomicAdd(&scnt[b], 1);
        pairs[sbase[b] + r] = ((unsigned)src[e] << 7) | (unsigned)(d & 127);
    }
}

// ---------- per-bucket counting sort -> CSR ----------
__global__ __launch_bounds__(256) void k_csr(
    const int* __restrict__ bktOff, const unsigned* __restrict__ pairs,
    int* __restrict__ rowstart, int* __restrict__ col)
{
    __shared__ unsigned sp[CAP];
    __shared__ int bins[BNODES], binpos[BNODES], stmp[BNODES];
    int tid = threadIdx.x;
    int bkt = blockIdx.x;
    int gbase = bktOff[bkt];
    int cnt = bktOff[bkt + 1] - gbase;
    if (tid < BNODES) bins[tid] = 0;
    __syncthreads();
    bool inl = (cnt <= CAP);
    if (inl) {
        for (int i = tid; i < cnt; i += 256) {
            unsigned u = pairs[gbase + i];
            sp[i] = u;
            atomicAdd(&bins[u & 127], 1);
        }
    } else {
        for (int i = tid; i < cnt; i += 256)
            atomicAdd(&bins[pairs[gbase + i] & 127], 1);
    }
    __syncthreads();
    if (tid < BNODES) stmp[tid] = bins[tid];
    __syncthreads();
    for (int off = 1; off < BNODES; off <<= 1) {
        int t = 0;
        if (tid < BNODES && tid >= off) t = stmp[tid - off];
        __syncthreads();
        if (tid < BNODES) stmp[tid] += t;
        __syncthreads();
    }
    if (tid < BNODES) {
        int ex = stmp[tid] - bins[tid];
        binpos[tid] = ex;
        int n = (bkt << 7) + tid;
        if (n < NN) rowstart[n] = gbase + ex;
        if (bkt == 0 && tid == 0) rowstart[NN] = NE;
    }
    __syncthreads();
    if (inl) {
        for (int i = tid; i < cnt; i += 256) {
            unsigned u = sp[i];
            int p = atomicAdd(&binpos[u & 127], 1);
            col[gbase + p] = (int)(u >> 7);
        }
    } else {
        for (int i = tid; i < cnt; i += 256) {
            unsigned u = pairs[gbase + i];
            int p = atomicAdd(&binpos[u & 127], 1);
            col[gbase + p] = (int)(u >> 7);
        }
    }
}

// ---------- CSR mean aggregation from fp8 rows (32B each), fp16 output ----------
// one wave per node; 4 lanes/edge x 8B loads -> 16 row-gathers (16 segments) per iter
__global__ __launch_bounds__(256) void k_agg8(const int* __restrict__ rowstart,
                                              const int* __restrict__ col,
                                              const uint2* __restrict__ hin,   // 4 uint2 per row
                                              __half2* __restrict__ aggh)      // 16 half2 per row
{
    int tid = blockIdx.x * 256 + threadIdx.x;
    int n = tid >> 6;
    if (n >= NN) return;
    int lane = threadIdx.x & 63;
    int q = lane & 3;       // 8B quarter (8 fp8 features) of the 32B row
    int grp = lane >> 2;    // edge group 0..15
    int rs = rowstart[n], re = rowstart[n + 1];
    float a0 = 0.0f, a1 = 0.0f, a2 = 0.0f, a3 = 0.0f;
    float a4 = 0.0f, a5 = 0.0f, a6 = 0.0f, a7 = 0.0f;
    for (int e = rs + grp; e < re; e += 16) {
        uint2 u = hin[(size_t)col[e] * 4 + q];
        auto f0 = __builtin_amdgcn_cvt_pk_f32_fp8(u.x, false);
        auto f1 = __builtin_amdgcn_cvt_pk_f32_fp8(u.x, true);
        auto f2 = __builtin_amdgcn_cvt_pk_f32_fp8(u.y, false);
        auto f3 = __builtin_amdgcn_cvt_pk_f32_fp8(u.y, true);
        a0 += f0[0]; a1 += f0[1]; a2 += f1[0]; a3 += f1[1];
        a4 += f2[0]; a5 += f2[1]; a6 += f3[0]; a7 += f3[1];
    }
    #pragma unroll
    for (int off = 4; off < 64; off <<= 1) {
        a0 += __shfl_xor(a0, off); a1 += __shfl_xor(a1, off);
        a2 += __shfl_xor(a2, off); a3 += __shfl_xor(a3, off);
        a4 += __shfl_xor(a4, off); a5 += __shfl_xor(a5, off);
        a6 += __shfl_xor(a6, off); a7 += __shfl_xor(a7, off);
    }
    if (lane < 4) {
        float inv = (re > rs) ? 1.0f / (float)(re - rs) : 0.0f;
        union { __half2 h[4]; uint4 u; } pk;
        pk.h[0] = __floats2half2_rn(a0 * inv, a1 * inv);
        pk.h[1] = __floats2half2_rn(a2 * inv, a3 * inv);
        pk.h[2] = __floats2half2_rn(a4 * inv, a5 * inv);
        pk.h[3] = __floats2half2_rn(a6 * inv, a7 * inv);
        ((uint4*)(aggh + (size_t)n * 16))[q] = pk.u;
    }
}

// ---------- layer-1 transform: h1(fp8) = bn(relu(agg@Wl^T + bl + x@Wr^T)) ----------
__global__ __launch_bounds__(256) void k_t1(
    const float* __restrict__ x, const __half2* __restrict__ aggh,
    const float* __restrict__ Wl, const float* __restrict__ bl, const float* __restrict__ Wr,
    const float* __restrict__ g, const float* __restrict__ b,
    const float* __restrict__ m, const float* __restrict__ v,
    unsigned* __restrict__ h1_8)
{
    __shared__ float sWl[FH * FI], sWr[FH * FI], sBias[FH], sScale[FH], sShift[FH];
    for (int i = threadIdx.x; i < FH * FI; i += 256) { sWl[i] = Wl[i]; sWr[i] = Wr[i]; }
    if (threadIdx.x < FH) {
        int j = threadIdx.x;
        float sc = g[j] * rsqrtf(v[j] + 1e-5f);
        sBias[j] = bl[j];
        sScale[j] = sc;
        sShift[j] = b[j] - m[j] * sc;
    }
    __syncthreads();
    int n = blockIdx.x * 256 + threadIdx.x;
    if (n >= NN) return;
    float xr[FI], ar[FI];
    #pragma unroll
    for (int k = 0; k < FI; k += 4) {
        float4 xv = *(const float4*)(x + (size_t)n * FI + k);
        xr[k] = xv.x; xr[k+1] = xv.y; xr[k+2] = xv.z; xr[k+3] = xv.w;
    }
    const __half2* arow = aggh + (size_t)n * 16;
    #pragma unroll
    for (int k2 = 0; k2 < 16; ++k2) {
        float2 fv = __half22float2(arow[k2]);
        ar[2 * k2] = fv.x; ar[2 * k2 + 1] = fv.y;
    }
    float res[32];
    for (int j = 0; j < FH; ++j) {
        float acc = sBias[j];
        #pragma unroll
        for (int k = 0; k < FI; ++k)
            acc += ar[k] * sWl[j * FI + k] + xr[k] * sWr[j * FI + k];
        acc = fmaxf(acc, 0.0f);
        res[j] = acc * sScale[j] + sShift[j];
    }
    res[30] = 0.0f; res[31] = 0.0f;
    unsigned* row = h1_8 + (size_t)n * 8;
    #pragma unroll
    for (int w = 0; w < 8; ++w) {
        unsigned pw = 0;
        pw = __builtin_amdgcn_cvt_pk_fp8_f32(res[4*w],   res[4*w+1], pw, false);
        pw = __builtin_amdgcn_cvt_pk_fp8_f32(res[4*w+2], res[4*w+3], pw, true);
        row[w] = pw;
    }
}

// ---------- fused layer-2 transform + per-graph dual pooling + MLP ----------
// one block per graph; per 8-node batch: stage agg(fp16)+self(fp8->f32) rows in LDS,
// thread (ng, f<30) computes bn(relu(...)) for its node's feature f, accumulates sum/max.
__global__ __launch_bounds__(256) void k_pool(
    const unsigned* __restrict__ h1_8, const __half2* __restrict__ aggh,
    const int* __restrict__ batch,
    const float* __restrict__ Wl, const float* __restrict__ bl, const float* __restrict__ Wr,
    const float* __restrict__ g, const float* __restrict__ b,
    const float* __restrict__ m, const float* __restrict__ v,
    const float* __restrict__ W1, const float* __restrict__ bb1,
    const float* __restrict__ W2, const float* __restrict__ bb2,
    float* __restrict__ out)
{
    __shared__ float sWl[FH * 33], sWr[FH * 33], sBias[FH], sScale[FH], sShift[FH];
    __shared__ float sAgg[8][33], sSelf[8][33];
    __shared__ float sS[8][FH], sM[8][FH], sz[2 * FH], st[10];
    int tid = threadIdx.x;
    for (int i = tid; i < FH * FH; i += 256) {
        int j = i / FH, k = i - j * FH;
        sWl[j * 33 + k] = Wl[i];
        sWr[j * 33 + k] = Wr[i];
    }
    if (tid < FH) {
        float sc = g[tid] * rsqrtf(v[tid] + 1e-5f);
        sBias[tid] = bl[tid];
        sScale[tid] = sc;
        sShift[tid] = b[tid] - m[tid] * sc;
    }
    __syncthreads();
    int gi = blockIdx.x;
    int lo = 0, hi = NN;
    while (lo < hi) { int mid = (lo + hi) >> 1; if (batch[mid] < gi) lo = mid + 1; else hi = mid; }
    int start = lo;
    hi = NN;
    while (lo < hi) { int mid = (lo + hi) >> 1; if (batch[mid] <= gi) lo = mid + 1; else hi = mid; }
    int end = lo;

    int f = tid & 31;
    int ng = tid >> 5;
    float sum = 0.0f, mx = -INFINITY;
    int cnt = end - start;
    int iters = (cnt + 7) >> 3;
    for (int it = 0; it < iters; ++it) {
        int n = start + (it << 3) + ng;
        bool valid = (n < end);
        if (valid) {
            if (f < 16) {                       // stage agg row (fp16)
                float2 fv = __half22float2(aggh[(size_t)n * 16 + f]);
                sAgg[ng][2 * f]     = fv.x;
                sAgg[ng][2 * f + 1] = fv.y;
            } else if (f < 24) {                // stage self row (fp8 -> f32)
                int w = f - 16;
                unsigned u = h1_8[(size_t)n * 8 + w];
                auto lo2 = __builtin_amdgcn_cvt_pk_f32_fp8(u, false);
                auto hi2 = __builtin_amdgcn_cvt_pk_f32_fp8(u, true);
                sSelf[ng][4 * w]     = lo2[0];
                sSelf[ng][4 * w + 1] = lo2[1];
                sSelf[ng][4 * w + 2] = hi2[0];
                sSelf[ng][4 * w + 3] = hi2[1];
            }
        }
        __syncthreads();
        if (valid && f < FH) {
            float acc = sBias[f];
            #pragma unroll
            for (int k = 0; k < FH; ++k)
                acc += sAgg[ng][k] * sWl[f * 33 + k] + sSelf[ng][k] * sWr[f * 33 + k];
            acc = fmaxf(acc, 0.0f);
            float val = acc * sScale[f] + sShift[f];
            sum += val;
            mx = fmaxf(mx, val);
        }
        __syncthreads();
    }
    if (f < FH) { sS[ng][f] = sum; sM[ng][f] = mx; }
    __syncthreads();
    if (tid < FH) {
        float s = 0.0f, mm = -INFINITY;
        #pragma unroll
        for (int w = 0; w < 8; ++w) { s += sS[w][tid]; mm = fmaxf(mm, sM[w][tid]); }
        sz[tid]      = (cnt > 0) ? mm : 0.0f;
        sz[FH + tid] = (cnt > 0) ? s / (float)cnt : 0.0f;
    }
    __syncthreads();
    if (tid < 10) {
        float t = bb1[tid];
        for (int k = 0; k < 2 * FH; ++k) t += sz[k] * W1[tid * 2 * FH + k];
        st[tid] = fmaxf(t, 0.0f);
    }
    __syncthreads();
    if (tid == 0) {
        float o = bb2[0];
        for (int j = 0; j < 10; ++j) o += st[j] * W2[j];
        out[gi] = 1.0f / (1.0f + expf(-o));
    }
}

extern "C" void kernel_launch(void* const* d_in, const int* in_sizes, int n_in,
                              void* d_out, int out_size, void* d_ws, size_t ws_size,
                              hipStream_t stream)
{
    const float* x   = (const float*)d_in[0];
    const int*   ei  = (const int*)d_in[1];
    const int*   bat = (const int*)d_in[2];
    const float* Wl1 = (const float*)d_in[3];
    const float* bl1 = (const float*)d_in[4];
    const float* Wr1 = (const float*)d_in[5];
    const float* Wl2 = (const float*)d_in[6];
    const float* bl2 = (const float*)d_in[7];
    const float* Wr2 = (const float*)d_in[8];
    const float* g1  = (const float*)d_in[9];
    const float* b1  = (const float*)d_in[10];
    const float* m1  = (const float*)d_in[11];
    const float* v1  = (const float*)d_in[12];
    const float* g2  = (const float*)d_in[13];
    const float* b2  = (const float*)d_in[14];
    const float* m2  = (const float*)d_in[15];
    const float* v2  = (const float*)d_in[16];
    const float* W1  = (const float*)d_in[17];
    const float* bb1 = (const float*)d_in[18];
    const float* W2  = (const float*)d_in[19];
    const float* bb2 = (const float*)d_in[20];

    const int* src = ei;
    const int* dst = ei + NE;

    // workspace layout (all regions 16B-aligned)
    unsigned short* partial = (unsigned short*)d_ws;                  // SCB*NBK ushort
    int* chunksum  = (int*)((char*)d_ws + (size_t)SCB * NBK * 2);     // NCHUNK*NBK
    int* bktOff    = chunksum + NCHUNK * NBK;                         // NBK+1 (+pad)
    int* rowstart  = bktOff + NBK + 2;                                // NN+1 (+pad)
    unsigned* pairs = (unsigned*)(rowstart + NN + 4);                 // NE
    int* col       = (int*)(pairs + NE);                              // NE
    unsigned* x8   = (unsigned*)(col + NE);                           // NN*8 words (fp8 rows)
    unsigned* h1_8 = x8 + (size_t)NN * 8;                             // NN*8 words
    __half2*  aggh = (__half2*)(h1_8 + (size_t)NN * 8);               // NN*16 half2

    k_phist<<<SCB + F8B, 256, 0, stream>>>(dst, partial, x, x8);

    {
        unsigned short* a0 = partial;
        int* a1 = chunksum;
        int* a2 = bktOff;
        void* args[] = { (void*)&a0, (void*)&a1, (void*)&a2 };
        hipLaunchCooperativeKernel((void*)k_prefix, dim3(PFB), dim3(256), args, 0, stream);
    }

    k_bscat<<<SCB, 256, 0, stream>>>(src, dst, partial, bktOff, pairs);
    k_csr  <<<NBK, 256, 0, stream>>>(bktOff, pairs, rowstart, col);

    int ab = (NN * 64 + 255) / 256;  // one wave per node
    k_agg8<<<ab, 256, 0, stream>>>(rowstart, col, (const uint2*)x8, aggh);
    k_t1<<<NB1, 256, 0, stream>>>(x, aggh, Wl1, bl1, Wr1, g1, b1, m1, v1, h1_8);
    k_agg8<<<ab, 256, 0, stream>>>(rowstart, col, (const uint2*)h1_8, aggh);
    k_pool<<<NG, 256, 0, stream>>>(h1_8, aggh, bat, Wl2, bl2, Wr2, g2, b2, m2, v2,
                                   W1, bb1, W2, bb2, (float*)d_out);
}

// Round 16
// 222.888 us; speedup vs baseline: 1.0353x; 1.0353x over previous
//
#include <hip/hip_runtime.h>
#include <hip/hip_fp16.h>
#include <hip/hip_cooperative_groups.h>

#define NN 100000
#define NE 1600000
#define FI 32
#define FH 30
#define PAD 32
#define NG 512
#define NBK 782      // ceil(NN/128) buckets of 128 consecutive dst nodes
#define BNODES 128
#define SCB 1024     // blocks for hist/scatter grid-stride
#define CBLK 32      // blocks per prefix chunk
#define NCHUNK (SCB / CBLK)   // 32
#define CAP 4096     // per-bucket LDS staging capacity (mean 2046)
#define NB1 391      // ceil(NN/256)
#define F8B 3125     // fp8-convert blocks: NN*8 words / 256
#define PFB 98       // prefix kernel blocks: ceil(NCHUNK*NBK/256)

// ---------- per-block bucket histogram (blocks < SCB) + x fp32->fp8 convert (rest) ----------
__global__ __launch_bounds__(256) void k_phist(const int* __restrict__ dst,
                                               unsigned short* __restrict__ partial,
                                               const float* __restrict__ x, unsigned* __restrict__ x8)
{
    __shared__ int cnt[NBK];
    if (blockIdx.x >= SCB) {
        int i = (blockIdx.x - SCB) * 256 + threadIdx.x;   // uint word = 4 fp8
        if (i < NN * 8) {
            float4 f = ((const float4*)x)[i];
            unsigned w = 0;
            w = __builtin_amdgcn_cvt_pk_fp8_f32(f.x, f.y, w, false);
            w = __builtin_amdgcn_cvt_pk_fp8_f32(f.z, f.w, w, true);
            x8[i] = w;
        }
        return;
    }
    for (int i = threadIdx.x; i < NBK; i += 256) cnt[i] = 0;
    __syncthreads();
    for (int e = blockIdx.x * 256 + threadIdx.x; e < NE; e += SCB * 256)
        atomicAdd(&cnt[dst[e] >> 7], 1);
    __syncthreads();
    for (int i = threadIdx.x; i < NBK; i += 256)
        partial[(size_t)blockIdx.x * NBK + i] = (unsigned short)cnt[i];
}

// ---------- fused prefix (cooperative): chunk sums -> bucket scan -> per-block bases ----------
__global__ __launch_bounds__(256) void k_prefix(unsigned short* __restrict__ partial,
                                                int* __restrict__ chunksum,
                                                int* __restrict__ bktOff)
{
    cooperative_groups::grid_group grid = cooperative_groups::this_grid();
    int t = blockIdx.x * 256 + threadIdx.x;
    int c = t / NBK, b = t - (t / NBK) * NBK;
    if (t < NCHUNK * NBK) {
        int s = 0;
        #pragma unroll 8
        for (int k = 0; k < CBLK; ++k)
            s += partial[(size_t)(c * CBLK + k) * NBK + b];
        chunksum[c * NBK + b] = s;
    }
    grid.sync();
    if (blockIdx.x == 0) {
        __shared__ int tot[NBK];
        int tid = threadIdx.x;
        for (int i = tid; i < NBK; i += 256) {
            int s = 0;
            for (int cc = 0; cc < NCHUNK; ++cc) s += chunksum[cc * NBK + i];
            tot[i] = s;
        }
        __syncthreads();
        for (int off = 1; off < NBK; off <<= 1) {
            int vals[(NBK + 255) / 256];
            for (int i = tid, j = 0; i < NBK; i += 256, ++j)
                vals[j] = (i >= off) ? tot[i - off] : 0;
            __syncthreads();
            for (int i = tid, j = 0; i < NBK; i += 256, ++j)
                tot[i] += vals[j];
            __syncthreads();
        }
        for (int i = tid; i < NBK; i += 256) bktOff[i + 1] = tot[i];
        if (tid == 0) bktOff[0] = 0;
    }
    if (t < NCHUNK * NBK) {
        int run = 0;
        for (int cc = 0; cc < c; ++cc) run += chunksum[cc * NBK + b];
        #pragma unroll 8
        for (int k = 0; k < CBLK; ++k) {
            size_t idx = (size_t)(c * CBLK + k) * NBK + b;
            int vv = partial[idx];
            partial[idx] = (unsigned short)run;
            run += vv;
        }
    }
}

// ---------- single-pass bucketed scatter using precomputed bases ----------
__global__ __launch_bounds__(256) void k_bscat(const int* __restrict__ src, const int* __restrict__ dst,
                                               const unsigned short* __restrict__ partial,
                                               const int* __restrict__ bktOff,
                                               unsigned* __restrict__ pairs)
{
    __shared__ int sbase[NBK];
    __shared__ int scnt[NBK];
    for (int i = threadIdx.x; i < NBK; i += 256) {
        sbase[i] = bktOff[i] + (int)partial[(size_t)blockIdx.x * NBK + i];
        scnt[i] = 0;
    }
    __syncthreads();
    for (int e = blockIdx.x * 256 + threadIdx.x; e < NE; e += SCB * 256) {
        int d = dst[e];
        int b = d >> 7;
        int r = atomicAdd(&scnt[b], 1);
        pairs[sbase[b] + r] = ((unsigned)src[e] << 7) | (unsigned)(d & 127);
    }
}

// ---------- per-bucket counting sort -> CSR ----------
__global__ __launch_bounds__(256) void k_csr(
    const int* __restrict__ bktOff, const unsigned* __restrict__ pairs,
    int* __restrict__ rowstart, int* __restrict__ col)
{
    __shared__ unsigned sp[CAP];
    __shared__ int bins[BNODES], binpos[BNODES], stmp[BNODES];
    int tid = threadIdx.x;
    int bkt = blockIdx.x;
    int gbase = bktOff[bkt];
    int cnt = bktOff[bkt + 1] - gbase;
    if (tid < BNODES) bins[tid] = 0;
    __syncthreads();
    bool inl = (cnt <= CAP);
    if (inl) {
        for (int i = tid; i < cnt; i += 256) {
            unsigned u = pairs[gbase + i];
            sp[i] = u;
            atomicAdd(&bins[u & 127], 1);
        }
    } else {
        for (int i = tid; i < cnt; i += 256)
            atomicAdd(&bins[pairs[gbase + i] & 127], 1);
    }
    __syncthreads();
    if (tid < BNODES) stmp[tid] = bins[tid];
    __syncthreads();
    for (int off = 1; off < BNODES; off <<= 1) {
        int t = 0;
        if (tid < BNODES && tid >= off) t = stmp[tid - off];
        __syncthreads();
        if (tid < BNODES) stmp[tid] += t;
        __syncthreads();
    }
    if (tid < BNODES) {
        int ex = stmp[tid] - bins[tid];
        binpos[tid] = ex;
        int n = (bkt << 7) + tid;
        if (n < NN) rowstart[n] = gbase + ex;
        if (bkt == 0 && tid == 0) rowstart[NN] = NE;
    }
    __syncthreads();
    if (inl) {
        for (int i = tid; i < cnt; i += 256) {
            unsigned u = sp[i];
            int p = atomicAdd(&binpos[u & 127], 1);
            col[gbase + p] = (int)(u >> 7);
        }
    } else {
        for (int i = tid; i < cnt; i += 256) {
            unsigned u = pairs[gbase + i];
            int p = atomicAdd(&binpos[u & 127], 1);
            col[gbase + p] = (int)(u >> 7);
        }
    }
}

// ---------- CSR mean aggregation from fp8 rows (32B each), fp16 output ----------
// one wave per node; 4 lanes/edge x 8B loads -> 16 row-gathers (16 segments) per iter
__global__ __launch_bounds__(256) void k_agg8(const int* __restrict__ rowstart,
                                              const int* __restrict__ col,
                                              const uint2* __restrict__ hin,   // 4 uint2 per row
                                              __half2* __restrict__ aggh)      // 16 half2 per row
{
    int tid = blockIdx.x * 256 + threadIdx.x;
    int n = tid >> 6;
    if (n >= NN) return;
    int lane = threadIdx.x & 63;
    int q = lane & 3;       // 8B quarter (8 fp8 features) of the 32B row
    int grp = lane >> 2;    // edge group 0..15
    int rs = rowstart[n], re = rowstart[n + 1];
    float a0 = 0.0f, a1 = 0.0f, a2 = 0.0f, a3 = 0.0f;
    float a4 = 0.0f, a5 = 0.0f, a6 = 0.0f, a7 = 0.0f;
    for (int e = rs + grp; e < re; e += 16) {
        uint2 u = hin[(size_t)col[e] * 4 + q];
        auto f0 = __builtin_amdgcn_cvt_pk_f32_fp8(u.x, false);
        auto f1 = __builtin_amdgcn_cvt_pk_f32_fp8(u.x, true);
        auto f2 = __builtin_amdgcn_cvt_pk_f32_fp8(u.y, false);
        auto f3 = __builtin_amdgcn_cvt_pk_f32_fp8(u.y, true);
        a0 += f0[0]; a1 += f0[1]; a2 += f1[0]; a3 += f1[1];
        a4 += f2[0]; a5 += f2[1]; a6 += f3[0]; a7 += f3[1];
    }
    #pragma unroll
    for (int off = 4; off < 64; off <<= 1) {
        a0 += __shfl_xor(a0, off); a1 += __shfl_xor(a1, off);
        a2 += __shfl_xor(a2, off); a3 += __shfl_xor(a3, off);
        a4 += __shfl_xor(a4, off); a5 += __shfl_xor(a5, off);
        a6 += __shfl_xor(a6, off); a7 += __shfl_xor(a7, off);
    }
    if (lane < 4) {
        float inv = (re > rs) ? 1.0f / (float)(re - rs) : 0.0f;
        union { __half2 h[4]; uint4 u; } pk;
        pk.h[0] = __floats2half2_rn(a0 * inv, a1 * inv);
        pk.h[1] = __floats2half2_rn(a2 * inv, a3 * inv);
        pk.h[2] = __floats2half2_rn(a4 * inv, a5 * inv);
        pk.h[3] = __floats2half2_rn(a6 * inv, a7 * inv);
        ((uint4*)(aggh + (size_t)n * 16))[q] = pk.u;
    }
}

// ---------- layer-1 transform: h1(fp8) = bn(relu(agg@Wl^T + bl + x@Wr^T)) ----------
__global__ __launch_bounds__(256) void k_t1(
    const float* __restrict__ x, const __half2* __restrict__ aggh,
    const float* __restrict__ Wl, const float* __restrict__ bl, const float* __restrict__ Wr,
    const float* __restrict__ g, const float* __restrict__ b,
    const float* __restrict__ m, const float* __restrict__ v,
    unsigned* __restrict__ h1_8)
{
    __shared__ float sWl[FH * FI], sWr[FH * FI], sBias[FH], sScale[FH], sShift[FH];
    for (int i = threadIdx.x; i < FH * FI; i += 256) { sWl[i] = Wl[i]; sWr[i] = Wr[i]; }
    if (threadIdx.x < FH) {
        int j = threadIdx.x;
        float sc = g[j] * rsqrtf(v[j] + 1e-5f);
        sBias[j] = bl[j];
        sScale[j] = sc;
        sShift[j] = b[j] - m[j] * sc;
    }
    __syncthreads();
    int n = blockIdx.x * 256 + threadIdx.x;
    if (n >= NN) return;
    float xr[FI], ar[FI];
    #pragma unroll
    for (int k = 0; k < FI; k += 4) {
        float4 xv = *(const float4*)(x + (size_t)n * FI + k);
        xr[k] = xv.x; xr[k+1] = xv.y; xr[k+2] = xv.z; xr[k+3] = xv.w;
    }
    const __half2* arow = aggh + (size_t)n * 16;
    #pragma unroll
    for (int k2 = 0; k2 < 16; ++k2) {
        float2 fv = __half22float2(arow[k2]);
        ar[2 * k2] = fv.x; ar[2 * k2 + 1] = fv.y;
    }
    float res[32];
    for (int j = 0; j < FH; ++j) {
        float acc = sBias[j];
        #pragma unroll
        for (int k = 0; k < FI; ++k)
            acc += ar[k] * sWl[j * FI + k] + xr[k] * sWr[j * FI + k];
        acc = fmaxf(acc, 0.0f);
        res[j] = acc * sScale[j] + sShift[j];
    }
    res[30] = 0.0f; res[31] = 0.0f;
    unsigned* row = h1_8 + (size_t)n * 8;
    #pragma unroll
    for (int w = 0; w < 8; ++w) {
        unsigned pw = 0;
        pw = __builtin_amdgcn_cvt_pk_fp8_f32(res[4*w],   res[4*w+1], pw, false);
        pw = __builtin_amdgcn_cvt_pk_fp8_f32(res[4*w+2], res[4*w+3], pw, true);
        row[w] = pw;
    }
}

// ---------- layer-2 transform: h2h(fp16) = bn(relu(agg@Wl^T + bl + h1@Wr^T)) ----------
__global__ __launch_bounds__(256) void k_t2(
    const unsigned* __restrict__ h1_8, const __half2* __restrict__ aggh,
    const float* __restrict__ Wl, const float* __restrict__ bl, const float* __restrict__ Wr,
    const float* __restrict__ g, const float* __restrict__ b,
    const float* __restrict__ m, const float* __restrict__ v,
    __half2* __restrict__ h2h)
{
    __shared__ float sWl[FH * FH], sWr[FH * FH], sBias[FH], sScale[FH], sShift[FH];
    for (int i = threadIdx.x; i < FH * FH; i += 256) { sWl[i] = Wl[i]; sWr[i] = Wr[i]; }
    if (threadIdx.x < FH) {
        int j = threadIdx.x;
        float sc = g[j] * rsqrtf(v[j] + 1e-5f);
        sBias[j] = bl[j];
        sScale[j] = sc;
        sShift[j] = b[j] - m[j] * sc;
    }
    __syncthreads();
    int n = blockIdx.x * 256 + threadIdx.x;
    if (n >= NN) return;
    float xr[32], ar[FH];
    const unsigned* hrow = h1_8 + (size_t)n * 8;
    #pragma unroll
    for (int w = 0; w < 8; ++w) {
        unsigned u = hrow[w];
        auto lo = __builtin_amdgcn_cvt_pk_f32_fp8(u, false);
        auto hi = __builtin_amdgcn_cvt_pk_f32_fp8(u, true);
        xr[4*w] = lo[0]; xr[4*w+1] = lo[1]; xr[4*w+2] = hi[0]; xr[4*w+3] = hi[1];
    }
    const __half2* arow = aggh + (size_t)n * 16;
    #pragma unroll
    for (int k2 = 0; k2 < FH / 2; ++k2) {
        float2 fv = __half22float2(arow[k2]);
        ar[2 * k2] = fv.x; ar[2 * k2 + 1] = fv.y;
    }
    float res[FH];
    for (int j = 0; j < FH; ++j) {
        float acc = sBias[j];
        #pragma unroll
        for (int k = 0; k < FH; ++k)
            acc += ar[k] * sWl[j * FH + k] + xr[k] * sWr[j * FH + k];
        acc = fmaxf(acc, 0.0f);
        res[j] = acc * sScale[j] + sShift[j];
    }
    __half2* row = h2h + (size_t)n * (PAD / 2);
    #pragma unroll
    for (int j = 0; j < FH; j += 2)
        row[j >> 1] = __floats2half2_rn(res[j], res[j + 1]);
}

// ---------- per-graph dual pooling + MLP (fp16 input) ----------
__global__ __launch_bounds__(256) void k_pool(
    const __half* __restrict__ h2, const int* __restrict__ batch,
    const float* __restrict__ W1, const float* __restrict__ bb1,
    const float* __restrict__ W2, const float* __restrict__ bb2,
    float* __restrict__ out)
{
    __shared__ float sS[8][FH], sM[8][FH], sz[2 * FH], st[10];
    int tid = threadIdx.x;
    int gi = blockIdx.x;
    int lo = 0, hi = NN;
    while (lo < hi) { int mid = (lo + hi) >> 1; if (batch[mid] < gi) lo = mid + 1; else hi = mid; }
    int start = lo;
    hi = NN;
    while (lo < hi) { int mid = (lo + hi) >> 1; if (batch[mid] <= gi) lo = mid + 1; else hi = mid; }
    int end = lo;

    int f = tid & 31;
    int ng = tid >> 5;
    float sum = 0.0f, mx = -INFINITY;
    if (f < FH) {
        for (int n = start + ng; n < end; n += 8) {
            float val = __half2float(h2[(size_t)n * PAD + f]);
            sum += val;
            mx = fmaxf(mx, val);
        }
        sS[ng][f] = sum;
        sM[ng][f] = mx;
    }
    __syncthreads();
    if (tid < FH) {
        float s = 0.0f, mm = -INFINITY;
        #pragma unroll
        for (int w = 0; w < 8; ++w) { s += sS[w][tid]; mm = fmaxf(mm, sM[w][tid]); }
        int c = end - start;
        sz[tid]      = (c > 0) ? mm : 0.0f;
        sz[FH + tid] = (c > 0) ? s / (float)c : 0.0f;
    }
    __syncthreads();
    if (tid < 10) {
        float t = bb1[tid];
        for (int k = 0; k < 2 * FH; ++k) t += sz[k] * W1[tid * 2 * FH + k];
        st[tid] = fmaxf(t, 0.0f);
    }
    __syncthreads();
    if (tid == 0) {
        float o = bb2[0];
        for (int j = 0; j < 10; ++j) o += st[j] * W2[j];
        out[gi] = 1.0f / (1.0f + expf(-o));
    }
}

extern "C" void kernel_launch(void* const* d_in, const int* in_sizes, int n_in,
                              void* d_out, int out_size, void* d_ws, size_t ws_size,
                              hipStream_t stream)
{
    const float* x   = (const float*)d_in[0];
    const int*   ei  = (const int*)d_in[1];
    const int*   bat = (const int*)d_in[2];
    const float* Wl1 = (const float*)d_in[3];
    const float* bl1 = (const float*)d_in[4];
    const float* Wr1 = (const float*)d_in[5];
    const float* Wl2 = (const float*)d_in[6];
    const float* bl2 = (const float*)d_in[7];
    const float* Wr2 = (const float*)d_in[8];
    const float* g1  = (const float*)d_in[9];
    const float* b1  = (const float*)d_in[10];
    const float* m1  = (const float*)d_in[11];
    const float* v1  = (const float*)d_in[12];
    const float* g2  = (const float*)d_in[13];
    const float* b2  = (const float*)d_in[14];
    const float* m2  = (const float*)d_in[15];
    const float* v2  = (const float*)d_in[16];
    const float* W1  = (const float*)d_in[17];
    const float* bb1 = (const float*)d_in[18];
    const float* W2  = (const float*)d_in[19];
    const float* bb2 = (const float*)d_in[20];

    const int* src = ei;
    const int* dst = ei + NE;

    // workspace layout (all regions 16B-aligned)
    unsigned short* partial = (unsigned short*)d_ws;                  // SCB*NBK ushort
    int* chunksum  = (int*)((char*)d_ws + (size_t)SCB * NBK * 2);     // NCHUNK*NBK
    int* bktOff    = chunksum + NCHUNK * NBK;                         // NBK+1 (+pad)
    int* rowstart  = bktOff + NBK + 2;                                // NN+1 (+pad)
    unsigned* pairs = (unsigned*)(rowstart + NN + 4);                 // NE
    int* col       = (int*)(pairs + NE);                              // NE
    unsigned* x8   = (unsigned*)(col + NE);                           // NN*8 words (fp8 rows)
    unsigned* h1_8 = x8 + (size_t)NN * 8;                             // NN*8 words
    __half2*  aggh = (__half2*)(h1_8 + (size_t)NN * 8);               // NN*16 half2
    __half2*  h2h  = aggh + (size_t)NN * 16;                          // NN*16 half2

    k_phist<<<SCB + F8B, 256, 0, stream>>>(dst, partial, x, x8);

    {
        unsigned short* a0 = partial;
        int* a1 = chunksum;
        int* a2 = bktOff;
        void* args[] = { (void*)&a0, (void*)&a1, (void*)&a2 };
        hipLaunchCooperativeKernel((void*)k_prefix, dim3(PFB), dim3(256), args, 0, stream);
    }

    k_bscat<<<SCB, 256, 0, stream>>>(src, dst, partial, bktOff, pairs);
    k_csr  <<<NBK, 256, 0, stream>>>(bktOff, pairs, rowstart, col);

    int ab = (NN * 64 + 255) / 256;  // one wave per node
    k_agg8<<<ab, 256, 0, stream>>>(rowstart, col, (const uint2*)x8, aggh);
    k_t1<<<NB1, 256, 0, stream>>>(x, aggh, Wl1, bl1, Wr1, g1, b1, m1, v1, h1_8);
    k_agg8<<<ab, 256, 0, stream>>>(rowstart, col, (const uint2*)h1_8, aggh);
    k_t2<<<NB1, 256, 0, stream>>>(h1_8, aggh, Wl2, bl2, Wr2, g2, b2, m2, v2, h2h);
    k_pool<<<NG, 256, 0, stream>>>((const __half*)h2h, bat, W1, bb1, W2, bb2, (float*)d_out);
}

// Round 17
// 181.835 us; speedup vs baseline: 1.2690x; 1.2258x over previous
//
#include <hip/hip_runtime.h>
#include <hip/hip_fp16.h>

#define NN 100000
#define NE 1600000
#define FI 32
#define FH 30
#define PAD 32
#define NG 512
#define NBK 782      // ceil(NN/128) buckets of 128 consecutive dst nodes
#define BNODES 128
#define SCB 1024     // blocks for hist/scatter grid-stride
#define CBLK 32      // blocks per prefix chunk
#define NCHUNK (SCB / CBLK)   // 32
#define CAP 4096     // per-bucket LDS staging capacity (mean 2046)
#define NB1 391      // ceil(NN/256)
#define F8B 3125     // fp8-convert blocks: NN*8 words / 256

// ---------- per-block bucket histogram (blocks < SCB) + x fp32->fp8 convert (rest) ----------
__global__ __launch_bounds__(256) void k_phist(const int* __restrict__ dst,
                                               unsigned short* __restrict__ partial,
                                               const float* __restrict__ x, unsigned* __restrict__ x8)
{
    __shared__ int cnt[NBK];
    if (blockIdx.x >= SCB) {
        int i = (blockIdx.x - SCB) * 256 + threadIdx.x;   // uint word = 4 fp8
        if (i < NN * 8) {
            float4 f = ((const float4*)x)[i];
            unsigned w = 0;
            w = __builtin_amdgcn_cvt_pk_fp8_f32(f.x, f.y, w, false);
            w = __builtin_amdgcn_cvt_pk_fp8_f32(f.z, f.w, w, true);
            x8[i] = w;
        }
        return;
    }
    for (int i = threadIdx.x; i < NBK; i += 256) cnt[i] = 0;
    __syncthreads();
    for (int e = blockIdx.x * 256 + threadIdx.x; e < NE; e += SCB * 256)
        atomicAdd(&cnt[dst[e] >> 7], 1);
    __syncthreads();
    for (int i = threadIdx.x; i < NBK; i += 256)
        partial[(size_t)blockIdx.x * NBK + i] = (unsigned short)cnt[i];
}

// ---------- chunk sums ----------
__global__ __launch_bounds__(256) void k_csum(const unsigned short* __restrict__ partial,
                                              int* __restrict__ chunksum)
{
    int t = blockIdx.x * 256 + threadIdx.x;
    if (t >= NCHUNK * NBK) return;
    int c = t / NBK, b = t - c * NBK;
    int s = 0;
    #pragma unroll 8
    for (int k = 0; k < CBLK; ++k)
        s += partial[(size_t)(c * CBLK + k) * NBK + b];
    chunksum[c * NBK + b] = s;
}

// ---------- bucket scan: bktOff + within-bucket chunk bases ----------
__global__ __launch_bounds__(1024) void k_cscan(const int* __restrict__ chunksum,
                                                int* __restrict__ chunkbase, int* __restrict__ bktOff)
{
    __shared__ int tmp[1024];
    int tid = threadIdx.x;
    int cs[NCHUNK];
    int total = 0;
    if (tid < NBK) {
        #pragma unroll
        for (int c = 0; c < NCHUNK; ++c) { cs[c] = chunksum[c * NBK + tid]; total += cs[c]; }
    }
    tmp[tid] = (tid < NBK) ? total : 0;
    __syncthreads();
    for (int off = 1; off < 1024; off <<= 1) {
        int t = (tid >= off) ? tmp[tid - off] : 0;
        __syncthreads();
        tmp[tid] += t;
        __syncthreads();
    }
    if (tid < NBK) {
        bktOff[tid] = tmp[tid] - total;   // exclusive bucket offset
        int run = 0;                      // within-bucket chunk base
        #pragma unroll
        for (int c = 0; c < NCHUNK; ++c) { chunkbase[c * NBK + tid] = run; run += cs[c]; }
    }
    if (tid == 0) bktOff[NBK] = NE;
}

// ---------- per-block bases (in-place prefix over ushort partial) ----------
__global__ __launch_bounds__(256) void k_base(unsigned short* __restrict__ partial,
                                              const int* __restrict__ chunkbase)
{
    int t = blockIdx.x * 256 + threadIdx.x;
    if (t >= NCHUNK * NBK) return;
    int c = t / NBK, b = t - c * NBK;
    int run = chunkbase[c * NBK + b];
    #pragma unroll 8
    for (int k = 0; k < CBLK; ++k) {
        size_t idx = (size_t)(c * CBLK + k) * NBK + b;
        int v = partial[idx];
        partial[idx] = (unsigned short)run;
        run += v;
    }
}

// ---------- single-pass bucketed scatter ----------
__global__ __launch_bounds__(256) void k_bscat(const int* __restrict__ src, const int* __restrict__ dst,
                                               const unsigned short* __restrict__ partial,
                                               const int* __restrict__ bktOff,
                                               unsigned* __restrict__ pairs)
{
    __shared__ int sbase[NBK];
    __shared__ int scnt[NBK];
    for (int i = threadIdx.x; i < NBK; i += 256) {
        sbase[i] = bktOff[i] + (int)partial[(size_t)blockIdx.x * NBK + i];
        scnt[i] = 0;
    }
    __syncthreads();
    for (int e = blockIdx.x * 256 + threadIdx.x; e < NE; e += SCB * 256) {
        int d = dst[e];
        int b = d >> 7;
        int r = atomicAdd(&scnt[b], 1);
        pairs[sbase[b] + r] = ((unsigned)src[e] << 7) | (unsigned)(d & 127);
    }
}

// ---------- per-bucket counting sort -> CSR ----------
__global__ __launch_bounds__(256) void k_csr(
    const int* __restrict__ bktOff, const unsigned* __restrict__ pairs,
    int* __restrict__ rowstart, int* __restrict__ col)
{
    __shared__ unsigned sp[CAP];
    __shared__ int bins[BNODES], binpos[BNODES], stmp[BNODES];
    int tid = threadIdx.x;
    int bkt = blockIdx.x;
    int gbase = bktOff[bkt];
    int cnt = bktOff[bkt + 1] - gbase;
    if (tid < BNODES) bins[tid] = 0;
    __syncthreads();
    bool inl = (cnt <= CAP);
    if (inl) {
        for (int i = tid; i < cnt; i += 256) {
            unsigned u = pairs[gbase + i];
            sp[i] = u;
            atomicAdd(&bins[u & 127], 1);
        }
    } else {
        for (int i = tid; i < cnt; i += 256)
            atomicAdd(&bins[pairs[gbase + i] & 127], 1);
    }
    __syncthreads();
    if (tid < BNODES) stmp[tid] = bins[tid];
    __syncthreads();
    for (int off = 1; off < BNODES; off <<= 1) {
        int t = 0;
        if (tid < BNODES && tid >= off) t = stmp[tid - off];
        __syncthreads();
        if (tid < BNODES) stmp[tid] += t;
        __syncthreads();
    }
    if (tid < BNODES) {
        int ex = stmp[tid] - bins[tid];
        binpos[tid] = ex;
        int n = (bkt << 7) + tid;
        if (n < NN) rowstart[n] = gbase + ex;
        if (bkt == 0 && tid == 0) rowstart[NN] = NE;
    }
    __syncthreads();
    if (inl) {
        for (int i = tid; i < cnt; i += 256) {
            unsigned u = sp[i];
            int p = atomicAdd(&binpos[u & 127], 1);
            col[gbase + p] = (int)(u >> 7);
        }
    } else {
        for (int i = tid; i < cnt; i += 256) {
            unsigned u = pairs[gbase + i];
            int p = atomicAdd(&binpos[u & 127], 1);
            col[gbase + p] = (int)(u >> 7);
        }
    }
}

// ---------- CSR mean aggregation from fp8 rows (32B each), fp16 output ----------
// one wave per node; 8 lanes/edge x 4B loads -> 8 contiguous 32B segments per wave-load,
// 3-step x 4-accumulator butterfly (vs 4-step x 8: reduction tree was the bottleneck)
__global__ __launch_bounds__(256) void k_agg8(const int* __restrict__ rowstart,
                                              const int* __restrict__ col,
                                              const unsigned* __restrict__ hin,  // 8 words per row
                                              __half2* __restrict__ aggh)        // 16 half2 per row
{
    int tid = blockIdx.x * 256 + threadIdx.x;
    int n = tid >> 6;
    if (n >= NN) return;
    int lane = threadIdx.x & 63;
    int q = lane & 7;       // 4B word (4 fp8 features) within the 32B row
    int grp = lane >> 3;    // edge group 0..7
    int rs = rowstart[n], re = rowstart[n + 1];
    float a0 = 0.0f, a1 = 0.0f, a2 = 0.0f, a3 = 0.0f;
    for (int e = rs + grp; e < re; e += 8) {
        unsigned u = hin[(size_t)col[e] * 8 + q];
        auto lo = __builtin_amdgcn_cvt_pk_f32_fp8(u, false);
        auto hi = __builtin_amdgcn_cvt_pk_f32_fp8(u, true);
        a0 += lo[0]; a1 += lo[1]; a2 += hi[0]; a3 += hi[1];
    }
    #pragma unroll
    for (int off = 8; off < 64; off <<= 1) {
        a0 += __shfl_xor(a0, off); a1 += __shfl_xor(a1, off);
        a2 += __shfl_xor(a2, off); a3 += __shfl_xor(a3, off);
    }
    if (lane < 8) {
        float inv = (re > rs) ? 1.0f / (float)(re - rs) : 0.0f;
        union { __half2 h[2]; uint2 u; } pk;
        pk.h[0] = __floats2half2_rn(a0 * inv, a1 * inv);
        pk.h[1] = __floats2half2_rn(a2 * inv, a3 * inv);
        ((uint2*)(aggh + (size_t)n * 16))[q] = pk.u;   // 8 lanes x 8B = one 64B row
    }
}

// ---------- layer-1 transform: h1(fp8) = bn(relu(agg@Wl^T + bl + x@Wr^T)) ----------
__global__ __launch_bounds__(256) void k_t1(
    const float* __restrict__ x, const __half2* __restrict__ aggh,
    const float* __restrict__ Wl, const float* __restrict__ bl, const float* __restrict__ Wr,
    const float* __restrict__ g, const float* __restrict__ b,
    const float* __restrict__ m, const float* __restrict__ v,
    unsigned* __restrict__ h1_8)
{
    __shared__ float sWl[FH * FI], sWr[FH * FI], sBias[FH], sScale[FH], sShift[FH];
    for (int i = threadIdx.x; i < FH * FI; i += 256) { sWl[i] = Wl[i]; sWr[i] = Wr[i]; }
    if (threadIdx.x < FH) {
        int j = threadIdx.x;
        float sc = g[j] * rsqrtf(v[j] + 1e-5f);
        sBias[j] = bl[j];
        sScale[j] = sc;
        sShift[j] = b[j] - m[j] * sc;
    }
    __syncthreads();
    int n = blockIdx.x * 256 + threadIdx.x;
    if (n >= NN) return;
    float xr[FI], ar[FI];
    #pragma unroll
    for (int k = 0; k < FI; k += 4) {
        float4 xv = *(const float4*)(x + (size_t)n * FI + k);
        xr[k] = xv.x; xr[k+1] = xv.y; xr[k+2] = xv.z; xr[k+3] = xv.w;
    }
    const __half2* arow = aggh + (size_t)n * 16;
    #pragma unroll
    for (int k2 = 0; k2 < 16; ++k2) {
        float2 fv = __half22float2(arow[k2]);
        ar[2 * k2] = fv.x; ar[2 * k2 + 1] = fv.y;
    }
    float res[32];
    for (int j = 0; j < FH; ++j) {
        float acc = sBias[j];
        #pragma unroll
        for (int k = 0; k < FI; ++k)
            acc += ar[k] * sWl[j * FI + k] + xr[k] * sWr[j * FI + k];
        acc = fmaxf(acc, 0.0f);
        res[j] = acc * sScale[j] + sShift[j];
    }
    res[30] = 0.0f; res[31] = 0.0f;
    unsigned* row = h1_8 + (size_t)n * 8;
    #pragma unroll
    for (int w = 0; w < 8; ++w) {
        unsigned pw = 0;
        pw = __builtin_amdgcn_cvt_pk_fp8_f32(res[4*w],   res[4*w+1], pw, false);
        pw = __builtin_amdgcn_cvt_pk_fp8_f32(res[4*w+2], res[4*w+3], pw, true);
        row[w] = pw;
    }
}

// ---------- layer-2 transform: h2h(fp16) = bn(relu(agg@Wl^T + bl + h1@Wr^T)) ----------
__global__ __launch_bounds__(256) void k_t2(
    const unsigned* __restrict__ h1_8, const __half2* __restrict__ aggh,
    const float* __restrict__ Wl, const float* __restrict__ bl, const float* __restrict__ Wr,
    const float* __restrict__ g, const float* __restrict__ b,
    const float* __restrict__ m, const float* __restrict__ v,
    __half2* __restrict__ h2h)
{
    __shared__ float sWl[FH * FH], sWr[FH * FH], sBias[FH], sScale[FH], sShift[FH];
    for (int i = threadIdx.x; i < FH * FH; i += 256) { sWl[i] = Wl[i]; sWr[i] = Wr[i]; }
    if (threadIdx.x < FH) {
        int j = threadIdx.x;
        float sc = g[j] * rsqrtf(v[j] + 1e-5f);
        sBias[j] = bl[j];
        sScale[j] = sc;
        sShift[j] = b[j] - m[j] * sc;
    }
    __syncthreads();
    int n = blockIdx.x * 256 + threadIdx.x;
    if (n >= NN) return;
    float xr[32], ar[FH];
    const unsigned* hrow = h1_8 + (size_t)n * 8;
    #pragma unroll
    for (int w = 0; w < 8; ++w) {
        unsigned u = hrow[w];
        auto lo = __builtin_amdgcn_cvt_pk_f32_fp8(u, false);
        auto hi = __builtin_amdgcn_cvt_pk_f32_fp8(u, true);
        xr[4*w] = lo[0]; xr[4*w+1] = lo[1]; xr[4*w+2] = hi[0]; xr[4*w+3] = hi[1];
    }
    const __half2* arow = aggh + (size_t)n * 16;
    #pragma unroll
    for (int k2 = 0; k2 < FH / 2; ++k2) {
        float2 fv = __half22float2(arow[k2]);
        ar[2 * k2] = fv.x; ar[2 * k2 + 1] = fv.y;
    }
    float res[FH];
    for (int j = 0; j < FH; ++j) {
        float acc = sBias[j];
        #pragma unroll
        for (int k = 0; k < FH; ++k)
            acc += ar[k] * sWl[j * FH + k] + xr[k] * sWr[j * FH + k];
        acc = fmaxf(acc, 0.0f);
        res[j] = acc * sScale[j] + sShift[j];
    }
    __half2* row = h2h + (size_t)n * (PAD / 2);
    #pragma unroll
    for (int j = 0; j < FH; j += 2)
        row[j >> 1] = __floats2half2_rn(res[j], res[j + 1]);
}

// ---------- per-graph dual pooling + MLP (fp16 input) ----------
__global__ __launch_bounds__(256) void k_pool(
    const __half* __restrict__ h2, const int* __restrict__ batch,
    const float* __restrict__ W1, const float* __restrict__ bb1,
    const float* __restrict__ W2, const float* __restrict__ bb2,
    float* __restrict__ out)
{
    __shared__ float sS[8][FH], sM[8][FH], sz[2 * FH], st[10];
    int tid = threadIdx.x;
    int gi = blockIdx.x;
    int lo = 0, hi = NN;
    while (lo < hi) { int mid = (lo + hi) >> 1; if (batch[mid] < gi) lo = mid + 1; else hi = mid; }
    int start = lo;
    hi = NN;
    while (lo < hi) { int mid = (lo + hi) >> 1; if (batch[mid] <= gi) lo = mid + 1; else hi = mid; }
    int end = lo;

    int f = tid & 31;
    int ng = tid >> 5;
    float sum = 0.0f, mx = -INFINITY;
    if (f < FH) {
        for (int n = start + ng; n < end; n += 8) {
            float val = __half2float(h2[(size_t)n * PAD + f]);
            sum += val;
            mx = fmaxf(mx, val);
        }
        sS[ng][f] = sum;
        sM[ng][f] = mx;
    }
    __syncthreads();
    if (tid < FH) {
        float s = 0.0f, mm = -INFINITY;
        #pragma unroll
        for (int w = 0; w < 8; ++w) { s += sS[w][tid]; mm = fmaxf(mm, sM[w][tid]); }
        int c = end - start;
        sz[tid]      = (c > 0) ? mm : 0.0f;
        sz[FH + tid] = (c > 0) ? s / (float)c : 0.0f;
    }
    __syncthreads();
    if (tid < 10) {
        float t = bb1[tid];
        for (int k = 0; k < 2 * FH; ++k) t += sz[k] * W1[tid * 2 * FH + k];
        st[tid] = fmaxf(t, 0.0f);
    }
    __syncthreads();
    if (tid == 0) {
        float o = bb2[0];
        for (int j = 0; j < 10; ++j) o += st[j] * W2[j];
        out[gi] = 1.0f / (1.0f + expf(-o));
    }
}

extern "C" void kernel_launch(void* const* d_in, const int* in_sizes, int n_in,
                              void* d_out, int out_size, void* d_ws, size_t ws_size,
                              hipStream_t stream)
{
    const float* x   = (const float*)d_in[0];
    const int*   ei  = (const int*)d_in[1];
    const int*   bat = (const int*)d_in[2];
    const float* Wl1 = (const float*)d_in[3];
    const float* bl1 = (const float*)d_in[4];
    const float* Wr1 = (const float*)d_in[5];
    const float* Wl2 = (const float*)d_in[6];
    const float* bl2 = (const float*)d_in[7];
    const float* Wr2 = (const float*)d_in[8];
    const float* g1  = (const float*)d_in[9];
    const float* b1  = (const float*)d_in[10];
    const float* m1  = (const float*)d_in[11];
    const float* v1  = (const float*)d_in[12];
    const float* g2  = (const float*)d_in[13];
    const float* b2  = (const float*)d_in[14];
    const float* m2  = (const float*)d_in[15];
    const float* v2  = (const float*)d_in[16];
    const float* W1  = (const float*)d_in[17];
    const float* bb1 = (const float*)d_in[18];
    const float* W2  = (const float*)d_in[19];
    const float* bb2 = (const float*)d_in[20];

    const int* src = ei;
    const int* dst = ei + NE;

    // workspace layout (all regions 16B-aligned)
    unsigned short* partial = (unsigned short*)d_ws;                  // SCB*NBK ushort
    int* chunksum  = (int*)((char*)d_ws + (size_t)SCB * NBK * 2);     // NCHUNK*NBK
    int* chunkbase = chunksum + NCHUNK * NBK;                         // NCHUNK*NBK
    int* bktOff    = chunkbase + NCHUNK * NBK;                        // NBK+1 (+pad)
    int* rowstart  = bktOff + NBK + 2;                                // NN+1 (+pad)
    unsigned* pairs = (unsigned*)(rowstart + NN + 4);                 // NE
    int* col       = (int*)(pairs + NE);                              // NE
    unsigned* x8   = (unsigned*)(col + NE);                           // NN*8 words (fp8 rows)
    unsigned* h1_8 = x8 + (size_t)NN * 8;                             // NN*8 words
    __half2*  aggh = (__half2*)(h1_8 + (size_t)NN * 8);               // NN*16 half2
    __half2*  h2h  = aggh + (size_t)NN * 16;                          // NN*16 half2

    int pb = (NCHUNK * NBK + 255) / 256;  // 98 blocks

    k_phist<<<SCB + F8B, 256, 0, stream>>>(dst, partial, x, x8);
    k_csum <<<pb, 256, 0, stream>>>(partial, chunksum);
    k_cscan<<<1, 1024, 0, stream>>>(chunksum, chunkbase, bktOff);
    k_base <<<pb, 256, 0, stream>>>(partial, chunkbase);
    k_bscat<<<SCB, 256, 0, stream>>>(src, dst, partial, bktOff, pairs);
    k_csr  <<<NBK, 256, 0, stream>>>(bktOff, pairs, rowstart, col);

    int ab = (NN * 64 + 255) / 256;  // one wave per node
    k_agg8<<<ab, 256, 0, stream>>>(rowstart, col, x8, aggh);
    k_t1<<<NB1, 256, 0, stream>>>(x, aggh, Wl1, bl1, Wr1, g1, b1, m1, v1, h1_8);
    k_agg8<<<ab, 256, 0, stream>>>(rowstart, col, h1_8, aggh);
    k_t2<<<NB1, 256, 0, stream>>>(h1_8, aggh, Wl2, bl2, Wr2, g2, b2, m2, v2, h2h);
    k_pool<<<NG, 256, 0, stream>>>((const __half*)h2h, bat, W1, bb1, W2, bb2, (float*)d_out);
}

// Round 18
// 181.407 us; speedup vs baseline: 1.2720x; 1.0024x over previous
//
#include <hip/hip_runtime.h>
#include <hip/hip_fp16.h>

#define NN 100000
#define NE 1600000
#define FI 32
#define FH 30
#define PAD 32
#define NG 512
#define NBK 782      // ceil(NN/128) buckets of 128 consecutive dst nodes
#define BNODES 128
#define SCB 2048     // blocks for hist/scatter grid-stride (8 blocks/CU)
#define CBLK 32      // blocks per prefix chunk
#define NCHUNK (SCB / CBLK)   // 64
#define CAP 4096     // per-bucket LDS staging capacity (mean 2046)
#define NB1 391      // ceil(NN/256)
#define F8B 3125     // fp8-convert blocks: NN*8 words / 256

// ---------- per-block bucket histogram (blocks < SCB) + x fp32->fp8 convert (rest) ----------
__global__ __launch_bounds__(256) void k_phist(const int* __restrict__ dst,
                                               unsigned short* __restrict__ partial,
                                               const float* __restrict__ x, unsigned* __restrict__ x8)
{
    __shared__ int cnt[NBK];
    if (blockIdx.x >= SCB) {
        int i = (blockIdx.x - SCB) * 256 + threadIdx.x;   // uint word = 4 fp8
        if (i < NN * 8) {
            float4 f = ((const float4*)x)[i];
            unsigned w = 0;
            w = __builtin_amdgcn_cvt_pk_fp8_f32(f.x, f.y, w, false);
            w = __builtin_amdgcn_cvt_pk_fp8_f32(f.z, f.w, w, true);
            x8[i] = w;
        }
        return;
    }
    for (int i = threadIdx.x; i < NBK; i += 256) cnt[i] = 0;
    __syncthreads();
    for (int e2 = blockIdx.x * 256 + threadIdx.x; e2 < NE / 2; e2 += SCB * 256) {
        int2 d2 = ((const int2*)dst)[e2];
        atomicAdd(&cnt[d2.x >> 7], 1);
        atomicAdd(&cnt[d2.y >> 7], 1);
    }
    __syncthreads();
    for (int i = threadIdx.x; i < NBK; i += 256)
        partial[(size_t)blockIdx.x * NBK + i] = (unsigned short)cnt[i];
}

// ---------- chunk sums ----------
__global__ __launch_bounds__(256) void k_csum(const unsigned short* __restrict__ partial,
                                              int* __restrict__ chunksum)
{
    int t = blockIdx.x * 256 + threadIdx.x;
    if (t >= NCHUNK * NBK) return;
    int c = t / NBK, b = t - c * NBK;
    int s = 0;
    #pragma unroll 8
    for (int k = 0; k < CBLK; ++k)
        s += partial[(size_t)(c * CBLK + k) * NBK + b];
    chunksum[c * NBK + b] = s;
}

// ---------- bucket scan: bktOff + within-bucket chunk bases ----------
__global__ __launch_bounds__(1024) void k_cscan(const int* __restrict__ chunksum,
                                                int* __restrict__ chunkbase, int* __restrict__ bktOff)
{
    __shared__ int tmp[1024];
    int tid = threadIdx.x;
    int total = 0;
    if (tid < NBK) {
        for (int c = 0; c < NCHUNK; ++c) total += chunksum[c * NBK + tid];
    }
    tmp[tid] = (tid < NBK) ? total : 0;
    __syncthreads();
    for (int off = 1; off < 1024; off <<= 1) {
        int t = (tid >= off) ? tmp[tid - off] : 0;
        __syncthreads();
        tmp[tid] += t;
        __syncthreads();
    }
    if (tid < NBK) {
        bktOff[tid] = tmp[tid] - total;   // exclusive bucket offset
        int run = 0;                      // within-bucket chunk base
        for (int c = 0; c < NCHUNK; ++c) {
            chunkbase[c * NBK + tid] = run;
            run += chunksum[c * NBK + tid];
        }
    }
    if (tid == 0) bktOff[NBK] = NE;
}

// ---------- per-block bases (in-place prefix over ushort partial) ----------
__global__ __launch_bounds__(256) void k_base(unsigned short* __restrict__ partial,
                                              const int* __restrict__ chunkbase)
{
    int t = blockIdx.x * 256 + threadIdx.x;
    if (t >= NCHUNK * NBK) return;
    int c = t / NBK, b = t - c * NBK;
    int run = chunkbase[c * NBK + b];
    #pragma unroll 8
    for (int k = 0; k < CBLK; ++k) {
        size_t idx = (size_t)(c * CBLK + k) * NBK + b;
        int v = partial[idx];
        partial[idx] = (unsigned short)run;
        run += v;
    }
}

// ---------- single-pass bucketed scatter ----------
__global__ __launch_bounds__(256) void k_bscat(const int* __restrict__ src, const int* __restrict__ dst,
                                               const unsigned short* __restrict__ partial,
                                               const int* __restrict__ bktOff,
                                               unsigned* __restrict__ pairs)
{
    __shared__ int sbase[NBK];
    __shared__ int scnt[NBK];
    for (int i = threadIdx.x; i < NBK; i += 256) {
        sbase[i] = bktOff[i] + (int)partial[(size_t)blockIdx.x * NBK + i];
        scnt[i] = 0;
    }
    __syncthreads();
    for (int e2 = blockIdx.x * 256 + threadIdx.x; e2 < NE / 2; e2 += SCB * 256) {
        int2 s2 = ((const int2*)src)[e2];
        int2 d2 = ((const int2*)dst)[e2];
        int b0 = d2.x >> 7;
        int r0 = atomicAdd(&scnt[b0], 1);
        pairs[sbase[b0] + r0] = ((unsigned)s2.x << 7) | (unsigned)(d2.x & 127);
        int b1 = d2.y >> 7;
        int r1 = atomicAdd(&scnt[b1], 1);
        pairs[sbase[b1] + r1] = ((unsigned)s2.y << 7) | (unsigned)(d2.y & 127);
    }
}

// ---------- per-bucket counting sort -> CSR ----------
__global__ __launch_bounds__(256) void k_csr(
    const int* __restrict__ bktOff, const unsigned* __restrict__ pairs,
    int* __restrict__ rowstart, int* __restrict__ col)
{
    __shared__ unsigned sp[CAP];
    __shared__ int bins[BNODES], binpos[BNODES], stmp[BNODES];
    int tid = threadIdx.x;
    int bkt = blockIdx.x;
    int gbase = bktOff[bkt];
    int cnt = bktOff[bkt + 1] - gbase;
    if (tid < BNODES) bins[tid] = 0;
    __syncthreads();
    bool inl = (cnt <= CAP);
    if (inl) {
        for (int i = tid; i < cnt; i += 256) {
            unsigned u = pairs[gbase + i];
            sp[i] = u;
            atomicAdd(&bins[u & 127], 1);
        }
    } else {
        for (int i = tid; i < cnt; i += 256)
            atomicAdd(&bins[pairs[gbase + i] & 127], 1);
    }
    __syncthreads();
    if (tid < BNODES) stmp[tid] = bins[tid];
    __syncthreads();
    for (int off = 1; off < BNODES; off <<= 1) {
        int t = 0;
        if (tid < BNODES && tid >= off) t = stmp[tid - off];
        __syncthreads();
        if (tid < BNODES) stmp[tid] += t;
        __syncthreads();
    }
    if (tid < BNODES) {
        int ex = stmp[tid] - bins[tid];
        binpos[tid] = ex;
        int n = (bkt << 7) + tid;
        if (n < NN) rowstart[n] = gbase + ex;
        if (bkt == 0 && tid == 0) rowstart[NN] = NE;
    }
    __syncthreads();
    if (inl) {
        for (int i = tid; i < cnt; i += 256) {
            unsigned u = sp[i];
            int p = atomicAdd(&binpos[u & 127], 1);
            col[gbase + p] = (int)(u >> 7);
        }
    } else {
        for (int i = tid; i < cnt; i += 256) {
            unsigned u = pairs[gbase + i];
            int p = atomicAdd(&binpos[u & 127], 1);
            col[gbase + p] = (int)(u >> 7);
        }
    }
}

// ---------- CSR mean aggregation from fp8 rows (32B each), fp16 output ----------
// one wave per node; 8 lanes/edge x 4B loads -> 8 contiguous 32B segments per wave-load
__global__ __launch_bounds__(256) void k_agg8(const int* __restrict__ rowstart,
                                              const int* __restrict__ col,
                                              const unsigned* __restrict__ hin,  // 8 words per row
                                              __half2* __restrict__ aggh)        // 16 half2 per row
{
    int tid = blockIdx.x * 256 + threadIdx.x;
    int n = tid >> 6;
    if (n >= NN) return;
    int lane = threadIdx.x & 63;
    int q = lane & 7;       // 4B word (4 fp8 features) within the 32B row
    int grp = lane >> 3;    // edge group 0..7
    int rs = rowstart[n], re = rowstart[n + 1];
    float a0 = 0.0f, a1 = 0.0f, a2 = 0.0f, a3 = 0.0f;
    for (int e = rs + grp; e < re; e += 8) {
        unsigned u = hin[(size_t)col[e] * 8 + q];
        auto lo = __builtin_amdgcn_cvt_pk_f32_fp8(u, false);
        auto hi = __builtin_amdgcn_cvt_pk_f32_fp8(u, true);
        a0 += lo[0]; a1 += lo[1]; a2 += hi[0]; a3 += hi[1];
    }
    #pragma unroll
    for (int off = 8; off < 64; off <<= 1) {
        a0 += __shfl_xor(a0, off); a1 += __shfl_xor(a1, off);
        a2 += __shfl_xor(a2, off); a3 += __shfl_xor(a3, off);
    }
    if (lane < 8) {
        float inv = (re > rs) ? 1.0f / (float)(re - rs) : 0.0f;
        union { __half2 h[2]; uint2 u; } pk;
        pk.h[0] = __floats2half2_rn(a0 * inv, a1 * inv);
        pk.h[1] = __floats2half2_rn(a2 * inv, a3 * inv);
        ((uint2*)(aggh + (size_t)n * 16))[q] = pk.u;   // 8 lanes x 8B = one 64B row
    }
}

// ---------- layer-1 transform: h1(fp8) = bn(relu(agg@Wl^T + bl + x@Wr^T)) ----------
__global__ __launch_bounds__(256) void k_t1(
    const float* __restrict__ x, const __half2* __restrict__ aggh,
    const float* __restrict__ Wl, const float* __restrict__ bl, const float* __restrict__ Wr,
    const float* __restrict__ g, const float* __restrict__ b,
    const float* __restrict__ m, const float* __restrict__ v,
    unsigned* __restrict__ h1_8)
{
    __shared__ float sWl[FH * FI], sWr[FH * FI], sBias[FH], sScale[FH], sShift[FH];
    for (int i = threadIdx.x; i < FH * FI; i += 256) { sWl[i] = Wl[i]; sWr[i] = Wr[i]; }
    if (threadIdx.x < FH) {
        int j = threadIdx.x;
        float sc = g[j] * rsqrtf(v[j] + 1e-5f);
        sBias[j] = bl[j];
        sScale[j] = sc;
        sShift[j] = b[j] - m[j] * sc;
    }
    __syncthreads();
    int n = blockIdx.x * 256 + threadIdx.x;
    if (n >= NN) return;
    float xr[FI], ar[FI];
    #pragma unroll
    for (int k = 0; k < FI; k += 4) {
        float4 xv = *(const float4*)(x + (size_t)n * FI + k);
        xr[k] = xv.x; xr[k+1] = xv.y; xr[k+2] = xv.z; xr[k+3] = xv.w;
    }
    const __half2* arow = aggh + (size_t)n * 16;
    #pragma unroll
    for (int k2 = 0; k2 < 16; ++k2) {
        float2 fv = __half22float2(arow[k2]);
        ar[2 * k2] = fv.x; ar[2 * k2 + 1] = fv.y;
    }
    float res[32];
    for (int j = 0; j < FH; ++j) {
        float acc = sBias[j];
        #pragma unroll
        for (int k = 0; k < FI; ++k)
            acc += ar[k] * sWl[j * FI + k] + xr[k] * sWr[j * FI + k];
        acc = fmaxf(acc, 0.0f);
        res[j] = acc * sScale[j] + sShift[j];
    }
    res[30] = 0.0f; res[31] = 0.0f;
    unsigned* row = h1_8 + (size_t)n * 8;
    #pragma unroll
    for (int w = 0; w < 8; ++w) {
        unsigned pw = 0;
        pw = __builtin_amdgcn_cvt_pk_fp8_f32(res[4*w],   res[4*w+1], pw, false);
        pw = __builtin_amdgcn_cvt_pk_fp8_f32(res[4*w+2], res[4*w+3], pw, true);
        row[w] = pw;
    }
}

// ---------- layer-2 transform: h2h(fp16) = bn(relu(agg@Wl^T + bl + h1@Wr^T)) ----------
__global__ __launch_bounds__(256) void k_t2(
    const unsigned* __restrict__ h1_8, const __half2* __restrict__ aggh,
    const float* __restrict__ Wl, const float* __restrict__ bl, const float* __restrict__ Wr,
    const float* __restrict__ g, const float* __restrict__ b,
    const float* __restrict__ m, const float* __restrict__ v,
    __half2* __restrict__ h2h)
{
    __shared__ float sWl[FH * FH], sWr[FH * FH], sBias[FH], sScale[FH], sShift[FH];
    for (int i = threadIdx.x; i < FH * FH; i += 256) { sWl[i] = Wl[i]; sWr[i] = Wr[i]; }
    if (threadIdx.x < FH) {
        int j = threadIdx.x;
        float sc = g[j] * rsqrtf(v[j] + 1e-5f);
        sBias[j] = bl[j];
        sScale[j] = sc;
        sShift[j] = b[j] - m[j] * sc;
    }
    __syncthreads();
    int n = blockIdx.x * 256 + threadIdx.x;
    if (n >= NN) return;
    float xr[32], ar[FH];
    const unsigned* hrow = h1_8 + (size_t)n * 8;
    #pragma unroll
    for (int w = 0; w < 8; ++w) {
        unsigned u = hrow[w];
        auto lo = __builtin_amdgcn_cvt_pk_f32_fp8(u, false);
        auto hi = __builtin_amdgcn_cvt_pk_f32_fp8(u, true);
        xr[4*w] = lo[0]; xr[4*w+1] = lo[1]; xr[4*w+2] = hi[0]; xr[4*w+3] = hi[1];
    }
    const __half2* arow = aggh + (size_t)n * 16;
    #pragma unroll
    for (int k2 = 0; k2 < FH / 2; ++k2) {
        float2 fv = __half22float2(arow[k2]);
        ar[2 * k2] = fv.x; ar[2 * k2 + 1] = fv.y;
    }
    float res[FH];
    for (int j = 0; j < FH; ++j) {
        float acc = sBias[j];
        #pragma unroll
        for (int k = 0; k < FH; ++k)
            acc += ar[k] * sWl[j * FH + k] + xr[k] * sWr[j * FH + k];
        acc = fmaxf(acc, 0.0f);
        res[j] = acc * sScale[j] + sShift[j];
    }
    __half2* row = h2h + (size_t)n * (PAD / 2);
    #pragma unroll
    for (int j = 0; j < FH; j += 2)
        row[j >> 1] = __floats2half2_rn(res[j], res[j + 1]);
}

// ---------- per-graph dual pooling + MLP (fp16 input) ----------
__global__ __launch_bounds__(256) void k_pool(
    const __half* __restrict__ h2, const int* __restrict__ batch,
    const float* __restrict__ W1, const float* __restrict__ bb1,
    const float* __restrict__ W2, const float* __restrict__ bb2,
    float* __restrict__ out)
{
    __shared__ float sS[8][FH], sM[8][FH], sz[2 * FH], st[10];
    int tid = threadIdx.x;
    int gi = blockIdx.x;
    int lo = 0, hi = NN;
    while (lo < hi) { int mid = (lo + hi) >> 1; if (batch[mid] < gi) lo = mid + 1; else hi = mid; }
    int start = lo;
    hi = NN;
    while (lo < hi) { int mid = (lo + hi) >> 1; if (batch[mid] <= gi) lo = mid + 1; else hi = mid; }
    int end = lo;

    int f = tid & 31;
    int ng = tid >> 5;
    float sum = 0.0f, mx = -INFINITY;
    if (f < FH) {
        for (int n = start + ng; n < end; n += 8) {
            float val = __half2float(h2[(size_t)n * PAD + f]);
            sum += val;
            mx = fmaxf(mx, val);
        }
        sS[ng][f] = sum;
        sM[ng][f] = mx;
    }
    __syncthreads();
    if (tid < FH) {
        float s = 0.0f, mm = -INFINITY;
        #pragma unroll
        for (int w = 0; w < 8; ++w) { s += sS[w][tid]; mm = fmaxf(mm, sM[w][tid]); }
        int c = end - start;
        sz[tid]      = (c > 0) ? mm : 0.0f;
        sz[FH + tid] = (c > 0) ? s / (float)c : 0.0f;
    }
    __syncthreads();
    if (tid < 10) {
        float t = bb1[tid];
        for (int k = 0; k < 2 * FH; ++k) t += sz[k] * W1[tid * 2 * FH + k];
        st[tid] = fmaxf(t, 0.0f);
    }
    __syncthreads();
    if (tid == 0) {
        float o = bb2[0];
        for (int j = 0; j < 10; ++j) o += st[j] * W2[j];
        out[gi] = 1.0f / (1.0f + expf(-o));
    }
}

extern "C" void kernel_launch(void* const* d_in, const int* in_sizes, int n_in,
                              void* d_out, int out_size, void* d_ws, size_t ws_size,
                              hipStream_t stream)
{
    const float* x   = (const float*)d_in[0];
    const int*   ei  = (const int*)d_in[1];
    const int*   bat = (const int*)d_in[2];
    const float* Wl1 = (const float*)d_in[3];
    const float* bl1 = (const float*)d_in[4];
    const float* Wr1 = (const float*)d_in[5];
    const float* Wl2 = (const float*)d_in[6];
    const float* bl2 = (const float*)d_in[7];
    const float* Wr2 = (const float*)d_in[8];
    const float* g1  = (const float*)d_in[9];
    const float* b1  = (const float*)d_in[10];
    const float* m1  = (const float*)d_in[11];
    const float* v1  = (const float*)d_in[12];
    const float* g2  = (const float*)d_in[13];
    const float* b2  = (const float*)d_in[14];
    const float* m2  = (const float*)d_in[15];
    const float* v2  = (const float*)d_in[16];
    const float* W1  = (const float*)d_in[17];
    const float* bb1 = (const float*)d_in[18];
    const float* W2  = (const float*)d_in[19];
    const float* bb2 = (const float*)d_in[20];

    const int* src = ei;
    const int* dst = ei + NE;

    // workspace layout (all regions 16B-aligned)
    unsigned short* partial = (unsigned short*)d_ws;                  // SCB*NBK ushort = 3.2MB
    int* chunksum  = (int*)((char*)d_ws + (size_t)SCB * NBK * 2);     // NCHUNK*NBK
    int* chunkbase = chunksum + NCHUNK * NBK;                         // NCHUNK*NBK
    int* bktOff    = chunkbase + NCHUNK * NBK;                        // NBK+1 (+pad)
    int* rowstart  = bktOff + NBK + 2;                                // NN+1 (+pad)
    unsigned* pairs = (unsigned*)(rowstart + NN + 4);                 // NE
    int* col       = (int*)(pairs + NE);                              // NE
    unsigned* x8   = (unsigned*)(col + NE);                           // NN*8 words (fp8 rows)
    unsigned* h1_8 = x8 + (size_t)NN * 8;                             // NN*8 words
    __half2*  aggh = (__half2*)(h1_8 + (size_t)NN * 8);               // NN*16 half2
    __half2*  h2h  = aggh + (size_t)NN * 16;                          // NN*16 half2

    int pb = (NCHUNK * NBK + 255) / 256;  // 196 blocks

    k_phist<<<SCB + F8B, 256, 0, stream>>>(dst, partial, x, x8);
    k_csum <<<pb, 256, 0, stream>>>(partial, chunksum);
    k_cscan<<<1, 1024, 0, stream>>>(chunksum, chunkbase, bktOff);
    k_base <<<pb, 256, 0, stream>>>(partial, chunkbase);
    k_bscat<<<SCB, 256, 0, stream>>>(src, dst, partial, bktOff, pairs);
    k_csr  <<<NBK, 256, 0, stream>>>(bktOff, pairs, rowstart, col);

    int ab = (NN * 64 + 255) / 256;  // one wave per node
    k_agg8<<<ab, 256, 0, stream>>>(rowstart, col, x8, aggh);
    k_t1<<<NB1, 256, 0, stream>>>(x, aggh, Wl1, bl1, Wr1, g1, b1, m1, v1, h1_8);
    k_agg8<<<ab, 256, 0, stream>>>(rowstart, col, h1_8, aggh);
    k_t2<<<NB1, 256, 0, stream>>>(h1_8, aggh, Wl2, bl2, Wr2, g2, b2, m2, v2, h2h);
    k_pool<<<NG, 256, 0, stream>>>((const __half*)h2h, bat, W1, bb1, W2, bb2, (float*)d_out);
}